// Round 5
// baseline (40.360 us; speedup 1.0000x reference)
//
#include <hip/hip_runtime.h>

typedef __bf16 bf16_t;
typedef __bf16 bf16x4 __attribute__((ext_vector_type(4)));
typedef __bf16 bf16x8 __attribute__((ext_vector_type(8)));
typedef float  f32x4  __attribute__((ext_vector_type(4)));

#define B_SZ  16
#define L_SEQ 2048
#define D_H   64
#define QB    64
#define KB    128

// softmax is over (S/8); fold log2(e)/8 into Q so MFMA output is in log2 units
#define QSCALE 0.18033688011112043f

__global__ __launch_bounds__(512, 2)
void attn_fwd_kernel(const float* __restrict__ Qg, const float* __restrict__ Kg,
                     const float* __restrict__ Vg, float* __restrict__ Og)
{
    // 256 blocks, 1/CU. XCD-aware: 2 batches per XCD (K+V fp32 = 2 MB -> L2).
    // Each block: q-tile pair (31-pi, pi) sequentially -> uniform 9 super-iters.
    const int lin = blockIdx.x;            // 0..255
    const int xcd = lin & 7;
    const int b   = xcd * 2 + ((lin >> 3) & 1);
    const int pi  = lin >> 4;              // 0..15

    const int tid  = threadIdx.x;
    const int grp  = tid >> 8;             // k-split group 0/1
    const int t8   = tid & 255;            // tid within group
    const int wig  = t8 >> 6;              // wave in group 0..3
    const int lane = tid & 63;
    const int lg   = lane >> 4;
    const int lc   = lane & 15;

    __shared__ __align__(16) bf16_t K_lds[2][2][KB][72];     // [grp][buf][k][d]   72 KB
    __shared__ __align__(16) bf16_t Vt_lds[2][2][D_H][136];  // [grp][buf][d][pos] 68 KB

    const size_t bbase = (size_t)b * L_SEQ * D_H;

    // V staging thread mapping (within group), phi-permuted column base
    const int vkb  = t8 & 31;
    const int vdg  = t8 >> 5;
    const int vpos = ((vkb >> 3) << 5) + ((vkb & 3) << 3) + (((vkb >> 2) & 1) << 2);

    f32x4 kreg[8], vreg[8];

    auto issueK = [&](int kt) {
        const int kbase = kt * KB;
#pragma unroll
        for (int i = 0; i < 8; ++i) {
            const int f = i * 256 + t8;
            const int r = f >> 4, c4 = (f & 15) * 4;
            kreg[i] = *reinterpret_cast<const f32x4*>(Kg + bbase + (size_t)(kbase + r) * D_H + c4);
        }
    };
    auto issueV = [&](int kt) {
        const int kbase = kt * KB;
#pragma unroll
        for (int d2 = 0; d2 < 2; ++d2)
#pragma unroll
            for (int i = 0; i < 4; ++i)
                vreg[d2 * 4 + i] = *reinterpret_cast<const f32x4*>(
                    Vg + bbase + (size_t)(kbase + vkb * 4 + i) * D_H + (vdg + d2 * 8) * 4);
    };
    auto writeK = [&](int buf) {
#pragma unroll
        for (int i = 0; i < 8; ++i) {
            const int f = i * 256 + t8;
            const int r = f >> 4, c4 = (f & 15) * 4;
            bf16x4 k4 = { (bf16_t)kreg[i][0], (bf16_t)kreg[i][1], (bf16_t)kreg[i][2], (bf16_t)kreg[i][3] };
            *reinterpret_cast<bf16x4*>(&K_lds[grp][buf][r][c4]) = k4;
        }
    };
    auto writeV = [&](int buf) {
#pragma unroll
        for (int d2 = 0; d2 < 2; ++d2) {
            const int db = vdg + d2 * 8;
#pragma unroll
            for (int j = 0; j < 4; ++j) {
                bf16x4 cj = { (bf16_t)vreg[d2 * 4 + 0][j], (bf16_t)vreg[d2 * 4 + 1][j],
                              (bf16_t)vreg[d2 * 4 + 2][j], (bf16_t)vreg[d2 * 4 + 3][j] };
                *reinterpret_cast<bf16x4*>(&Vt_lds[grp][buf][db * 4 + j][vpos]) = cj;
            }
        }
    };

    for (int hv = 0; hv < 2; ++hv) {
        const int qt  = hv ? pi : (31 - pi);
        const int nkt = (qt + 2) >> 1;            // 128-wide K tiles (last masked)
        const int nsG = (nkt + 1 - grp) >> 1;     // this group's tile count (tiles 2s+grp)
        const int ns0 = (nkt + 1) >> 1;           // lockstep super-iteration count

        // ---- Q fragment (B-operand of swapped QK: lane lc <-> q, (lg,j) <-> d) ----
        const int qrow = qt * QB + wig * 16 + lc;
        bf16x8 qa[2];
#pragma unroll
        for (int h = 0; h < 2; ++h) {
            const float* qp = Qg + bbase + (size_t)qrow * D_H + h * 32 + lg * 8;
            const f32x4 f0 = *reinterpret_cast<const f32x4*>(qp);
            const f32x4 f1 = *reinterpret_cast<const f32x4*>(qp + 4);
            bf16x8 a;
#pragma unroll
            for (int j = 0; j < 4; ++j) { a[j] = (bf16_t)(f0[j] * QSCALE); a[4 + j] = (bf16_t)(f1[j] * QSCALE); }
            qa[h] = a;
        }

        // O^T accumulator: o[dt][r] = O[d = dt*16 + lg*4 + r][q = qrow]
        f32x4 o[4];
#pragma unroll
        for (int dt = 0; dt < 4; ++dt) o[dt] = (f32x4){0.f, 0.f, 0.f, 0.f};
        float m = -1e30f, l = 0.f;

        // ---- prologue: each group stages its first tile ----
        if (nsG > 0) { issueK(grp); issueV(grp); writeK(0); writeV(0); }
        __syncthreads();

        int cur = 0;
        for (int s = 0; s < ns0; ++s) {
            if (s < nsG) {
                const int kt    = 2 * s + grp;
                const int kbase = kt * KB;
                const bool more = (s + 1 < nsG);
                if (more) issueK(2 * (s + 1) + grp);

                // ---- S^T = K Q^T: s[n][r] = S[k=kbase+n*16+lg*4+r][q=qrow] ----
                f32x4 sc[8];
                __builtin_amdgcn_s_setprio(1);
#pragma unroll
                for (int n = 0; n < 8; ++n) {
                    f32x4 acc = (f32x4){0.f, 0.f, 0.f, 0.f};
#pragma unroll
                    for (int h = 0; h < 2; ++h) {
                        const bf16x8 kb = *reinterpret_cast<const bf16x8*>(&K_lds[grp][cur][n * 16 + lc][h * 32 + lg * 8]);
                        acc = __builtin_amdgcn_mfma_f32_16x16x32_bf16(kb, qa[h], acc, 0, 0, 0);
                    }
                    sc[n] = acc;
                }
                __builtin_amdgcn_s_setprio(0);
                if (more) issueV(2 * (s + 1) + grp);
                if (kt == nkt - 1) {
#pragma unroll
                    for (int n = 0; n < 8; ++n)
#pragma unroll
                        for (int r = 0; r < 4; ++r)
                            if (kbase + n * 16 + lg * 4 + r > qrow) sc[n][r] = -1e30f;
                }

                // ---- per-lane online softmax for q = qrow ----
                float mx = -1e30f;
#pragma unroll
                for (int n = 0; n < 8; ++n)
                    mx = fmaxf(fmaxf(mx, sc[n][0]), fmaxf(sc[n][1], fmaxf(sc[n][2], sc[n][3])));
                mx = fmaxf(mx, __shfl_xor(mx, 16));
                mx = fmaxf(mx, __shfl_xor(mx, 32));
                const float mn = fmaxf(m, mx);
                const float alpha = exp2f(m - mn);
                m = mn;
                // P packed directly into the PV B-operand layout (phi-permuted V^T)
                bf16x8 w[4];
                float rs = 0.f;
#pragma unroll
                for (int n = 0; n < 8; ++n) {
                    const float p0 = exp2f(sc[n][0] - mn), p1 = exp2f(sc[n][1] - mn);
                    const float p2 = exp2f(sc[n][2] - mn), p3 = exp2f(sc[n][3] - mn);
                    rs += (p0 + p1) + (p2 + p3);
                    const int wi = n >> 1, off = (n & 1) * 4;
                    w[wi][off + 0] = (bf16_t)p0; w[wi][off + 1] = (bf16_t)p1;
                    w[wi][off + 2] = (bf16_t)p2; w[wi][off + 3] = (bf16_t)p3;
                }
                rs += __shfl_xor(rs, 16);
                rs += __shfl_xor(rs, 32);
                l = l * alpha + rs;
#pragma unroll
                for (int dt = 0; dt < 4; ++dt)
#pragma unroll
                    for (int r = 0; r < 4; ++r) o[dt][r] *= alpha;

                if (more) writeK(cur ^ 1);   // free kreg before PV

                // ---- O^T += V^T P : P straight from registers ----
                __builtin_amdgcn_s_setprio(1);
#pragma unroll
                for (int ks = 0; ks < 4; ++ks) {
#pragma unroll
                    for (int dt = 0; dt < 4; ++dt) {
                        const bf16x8 vb = *reinterpret_cast<const bf16x8*>(&Vt_lds[grp][cur][dt * 16 + lc][ks * 32 + lg * 8]);
                        o[dt] = __builtin_amdgcn_mfma_f32_16x16x32_bf16(vb, w[ks], o[dt], 0, 0, 0);
                    }
                }
                __builtin_amdgcn_s_setprio(0);

                if (more) writeV(cur ^ 1);
            }
            __syncthreads();
            cur ^= 1;
        }

        // ---- merge the two groups' (m, l, O^T) via LDS overlay on K_lds[0] ----
        float* mrg  = reinterpret_cast<float*>(&K_lds[0][0][0][0]);
        float* obuf = mrg;                   // [64][68] floats
        float* mbuf = mrg + 64 * 68;         // [64]
        float* lbuf = mrg + 64 * 68 + 64;    // [64]
        const int qq = wig * 16 + lc;
        if (grp == 1) {
#pragma unroll
            for (int dt = 0; dt < 4; ++dt)
                *reinterpret_cast<f32x4*>(&obuf[qq * 68 + dt * 16 + lg * 4]) = o[dt];
            if (lg == 0) { mbuf[qq] = m; lbuf[qq] = l; }
        }
        __syncthreads();
        if (grp == 0) {
            const float m1 = mbuf[qq], l1 = lbuf[qq];
            const float mt = fmaxf(m, m1);
            const float a0 = exp2f(m - mt), a1 = exp2f(m1 - mt);
            const float linv = 1.0f / (l * a0 + l1 * a1);
#pragma unroll
            for (int dt = 0; dt < 4; ++dt) {
                const f32x4 o1 = *reinterpret_cast<const f32x4*>(&obuf[qq * 68 + dt * 16 + lg * 4]);
                f32x4 val;
#pragma unroll
                for (int r = 0; r < 4; ++r) val[r] = (o[dt][r] * a0 + o1[r] * a1) * linv;
                *reinterpret_cast<f32x4*>(Og + bbase + (size_t)qrow * D_H + dt * 16 + lg * 4) = val;
            }
        }
        __syncthreads();   // merge area free before next q-tile's prologue writes
    }
}

extern "C" void kernel_launch(void* const* d_in, const int* in_sizes, int n_in,
                              void* d_out, int out_size, void* d_ws, size_t ws_size,
                              hipStream_t stream)
{
    const float* Q = (const float*)d_in[0];
    const float* K = (const float*)d_in[1];
    const float* V = (const float*)d_in[2];
    float* O = (float*)d_out;
    attn_fwd_kernel<<<dim3(256), dim3(512), 0, stream>>>(Q, K, V, O);
}

// Round 6
// 40.144 us; speedup vs baseline: 1.0054x; 1.0054x over previous
//
#include <hip/hip_runtime.h>

typedef __bf16 bf16_t;
typedef __bf16 bf16x4 __attribute__((ext_vector_type(4)));
typedef __bf16 bf16x8 __attribute__((ext_vector_type(8)));
typedef float  f32x4  __attribute__((ext_vector_type(4)));

#define B_SZ  16
#define L_SEQ 2048
#define D_H   64
#define QB    64
#define KB    128

// softmax is over (S/8); fold log2(e)/8 into Q so MFMA output is in log2 units
#define QSCALE 0.18033688011112043f

__global__ __launch_bounds__(256, 2)
void attn_fwd_kernel(const float* __restrict__ Qg, const float* __restrict__ Kg,
                     const float* __restrict__ Vg, float* __restrict__ Og)
{
    // XCD-aware decode: 2 batches per XCD (K+V fp32 = 2 MB -> fits 4 MB L2),
    // balanced qt pairing: co-resident blocks get qt=31-qi and qt=qi.
    const int lin  = blockIdx.x;          // 0..511
    const int xcd  = lin & 7;
    const int slot = lin >> 3;            // 0..63
    const int half = slot >> 5;
    const int qi   = slot & 31;
    const int b    = xcd * 2 + half;
    const int qt   = half ? qi : (31 - qi);

    const int tid  = threadIdx.x;
    const int lane = tid & 63;
    const int lg   = lane >> 4;    // lane group 0..3
    const int lc   = lane & 15;
    const int lc7  = lc & 7;

    // XOR-swizzled tiles: element (row, d/pos) lives at halfword
    //   row*RW + ((chunk ^ (row&7))*8) + within   (chunk = col>>3)
    __shared__ __align__(16) bf16_t K_lds[2][KB * D_H];    // [buf][128*64]  32 KB
    __shared__ __align__(16) bf16_t Vt_lds[2][D_H * KB];   // [buf][64*128]  32 KB

    const size_t bbase = (size_t)b * L_SEQ * D_H;

    // ---- Q fragment (B-operand of swapped QK: lane lc <-> q, (lg,j) <-> d) ----
    const int qrow = qt * QB + (tid >> 6) * 16 + lc;
    bf16x8 qa[2];
#pragma unroll
    for (int h = 0; h < 2; ++h) {
        const float* qp = Qg + bbase + (size_t)qrow * D_H + h * 32 + lg * 8;
        const f32x4 f0 = *reinterpret_cast<const f32x4*>(qp);
        const f32x4 f1 = *reinterpret_cast<const f32x4*>(qp + 4);
        bf16x8 a;
#pragma unroll
        for (int j = 0; j < 4; ++j) { a[j] = (bf16_t)(f0[j] * QSCALE); a[4 + j] = (bf16_t)(f1[j] * QSCALE); }
        qa[h] = a;
    }

    // O^T accumulator: o[dt][r] = O[d = dt*16 + lg*4 + r][q = qrow]
    f32x4 o[4];
#pragma unroll
    for (int dt = 0; dt < 4; ++dt) o[dt] = (f32x4){0.f, 0.f, 0.f, 0.f};
    float m = -1e30f, l = 0.f;   // l is a PER-LANE partial (this lane's k-slots), frame m

    const int nkt = (qt + 2) >> 1;        // number of 128-wide K tiles (last one masked)

    // ---- staging: K as b128 chunks, V transposed 4x4 blocks; both XOR-swizzled ----
    const int vkb  = tid & 31;            // k-block (4 rows) 0..31
    const int vdg  = tid >> 5;            // 0..7 -> d-blocks vdg, vdg+8
    const int vpos = ((vkb >> 3) << 5) + ((vkb & 3) << 3) + (((vkb >> 2) & 1) << 2);

    f32x4 kreg[8], vreg[8];

    auto issueK = [&](int kt) {
        const int kbase = kt * KB;
#pragma unroll
        for (int i = 0; i < 4; ++i) {
            const int u = i * 256 + tid;          // bf16x8-chunk id 0..1023
            const int r = u >> 3, ch = u & 7;
            const float* p = Kg + bbase + (size_t)(kbase + r) * D_H + ch * 8;
            kreg[2 * i]     = *reinterpret_cast<const f32x4*>(p);
            kreg[2 * i + 1] = *reinterpret_cast<const f32x4*>(p + 4);
        }
    };
    auto issueV = [&](int kt) {
        const int kbase = kt * KB;
#pragma unroll
        for (int d2 = 0; d2 < 2; ++d2)
#pragma unroll
            for (int i = 0; i < 4; ++i)
                vreg[d2 * 4 + i] = *reinterpret_cast<const f32x4*>(
                    Vg + bbase + (size_t)(kbase + vkb * 4 + i) * D_H + (vdg + d2 * 8) * 4);
    };
    auto writeK = [&](int buf) {
#pragma unroll
        for (int i = 0; i < 4; ++i) {
            const int u = i * 256 + tid;
            const int r = u >> 3, ch = u & 7;
            bf16x8 kk;
#pragma unroll
            for (int j = 0; j < 4; ++j) { kk[j] = (bf16_t)kreg[2 * i][j]; kk[4 + j] = (bf16_t)kreg[2 * i + 1][j]; }
            *reinterpret_cast<bf16x8*>(&K_lds[buf][r * 64 + ((ch ^ (r & 7)) << 3)]) = kk;
        }
    };
    auto writeV = [&](int buf) {
#pragma unroll
        for (int d2 = 0; d2 < 2; ++d2) {
            const int db = vdg + d2 * 8;
#pragma unroll
            for (int j = 0; j < 4; ++j) {
                const int d = db * 4 + j;
                bf16x4 cj = { (bf16_t)vreg[d2 * 4 + 0][j], (bf16_t)vreg[d2 * 4 + 1][j],
                              (bf16_t)vreg[d2 * 4 + 2][j], (bf16_t)vreg[d2 * 4 + 3][j] };
                const int hw = d * 128 + (((vpos >> 3) ^ (d & 7)) << 3) + (vpos & 7);
                *reinterpret_cast<bf16x4*>(&Vt_lds[buf][hw]) = cj;
            }
        }
    };

    // ---- main loop: double-buffered, 1 barrier/iter, loads in flight across compute ----
    issueK(0); issueV(0); writeK(0); writeV(0);
    __syncthreads();
    int cur = 0;
    for (int kt = 0; kt < nkt; ++kt) {
        const bool last = (kt == nkt - 1);
        const int kbase = kt * KB;
        if (!last) issueK(kt + 1);

        // ---- S^T = K Q^T (log2 units): s[n][r] = S[k=kbase+n*16+lg*4+r][q=qrow] ----
        f32x4 sc[8];
        __builtin_amdgcn_s_setprio(1);
#pragma unroll
        for (int n = 0; n < 8; ++n) {
            f32x4 acc = (f32x4){0.f, 0.f, 0.f, 0.f};
#pragma unroll
            for (int h = 0; h < 2; ++h) {
                const int hw = (n * 16 + lc) * 64 + ((((h << 2) | lg) ^ lc7) << 3);
                const bf16x8 kb = *reinterpret_cast<const bf16x8*>(&K_lds[cur][hw]);
                acc = __builtin_amdgcn_mfma_f32_16x16x32_bf16(kb, qa[h], acc, 0, 0, 0);
            }
            sc[n] = acc;
        }
        __builtin_amdgcn_s_setprio(0);
        if (!last) issueV(kt + 1);
        if (last) {
#pragma unroll
            for (int n = 0; n < 8; ++n)
#pragma unroll
                for (int r = 0; r < 4; ++r)
                    if (kbase + n * 16 + lg * 4 + r > qrow) sc[n][r] = -1e30f;
        }

        // ---- defer-max online softmax (per-lane; cross-lane only on slow path) ----
        float mxp = fmaxf(fmaxf(sc[0][0], sc[0][1]), fmaxf(sc[0][2], sc[0][3]));
#pragma unroll
        for (int n = 1; n < 8; ++n)
            mxp = fmaxf(mxp, fmaxf(fmaxf(sc[n][0], sc[n][1]), fmaxf(sc[n][2], sc[n][3])));
        if (!__all(mxp <= m + 8.0f)) {        // slow path: genuine new max (rare)
            float mx = mxp;
            mx = fmaxf(mx, __shfl_xor(mx, 16));
            mx = fmaxf(mx, __shfl_xor(mx, 32));
            const float mn = fmaxf(m, mx);
            const float alpha = exp2f(m - mn);
            m = mn;
            l *= alpha;
#pragma unroll
            for (int dt = 0; dt < 4; ++dt)
#pragma unroll
                for (int r = 0; r < 4; ++r) o[dt][r] *= alpha;
        }
        // P in the PV B-operand layout; l accumulates per-lane in frame m
        bf16x8 w[4];
        float rs = 0.f;
#pragma unroll
        for (int n = 0; n < 8; ++n) {
            const float p0 = exp2f(sc[n][0] - m), p1 = exp2f(sc[n][1] - m);
            const float p2 = exp2f(sc[n][2] - m), p3 = exp2f(sc[n][3] - m);
            rs += (p0 + p1) + (p2 + p3);
            const int wi = n >> 1, off = (n & 1) * 4;
            w[wi][off + 0] = (bf16_t)p0; w[wi][off + 1] = (bf16_t)p1;
            w[wi][off + 2] = (bf16_t)p2; w[wi][off + 3] = (bf16_t)p3;
        }
        l += rs;

        if (!last) writeK(cur ^ 1);   // free kreg before PV

        // ---- O^T += V^T P : P straight from registers, V^T from swizzled LDS ----
        __builtin_amdgcn_s_setprio(1);
#pragma unroll
        for (int ks = 0; ks < 4; ++ks) {
#pragma unroll
            for (int dt = 0; dt < 4; ++dt) {
                const int hw = (dt * 16 + lc) * 128 + ((((ks << 2) | lg) ^ lc7) << 3);
                const bf16x8 vb = *reinterpret_cast<const bf16x8*>(&Vt_lds[cur][hw]);
                o[dt] = __builtin_amdgcn_mfma_f32_16x16x32_bf16(vb, w[ks], o[dt], 0, 0, 0);
            }
        }
        __builtin_amdgcn_s_setprio(0);

        if (!last) writeV(cur ^ 1);
        __syncthreads();
        cur ^= 1;
    }

    // ---- epilogue: reduce per-lane l across the 4 lane-groups, then O = O^T / l ----
    float lr = l;
    lr += __shfl_xor(lr, 16);
    lr += __shfl_xor(lr, 32);
    const float inv = 1.0f / lr;
#pragma unroll
    for (int dt = 0; dt < 4; ++dt) {
        f32x4 val = { o[dt][0] * inv, o[dt][1] * inv, o[dt][2] * inv, o[dt][3] * inv };
        *reinterpret_cast<f32x4*>(Og + bbase + (size_t)qrow * D_H + dt * 16 + lg * 4) = val;
    }
}

extern "C" void kernel_launch(void* const* d_in, const int* in_sizes, int n_in,
                              void* d_out, int out_size, void* d_ws, size_t ws_size,
                              hipStream_t stream)
{
    const float* Q = (const float*)d_in[0];
    const float* K = (const float*)d_in[1];
    const float* V = (const float*)d_in[2];
    float* O = (float*)d_out;
    attn_fwd_kernel<<<dim3(512), dim3(256), 0, stream>>>(Q, K, V, O);
}